// Round 6
// baseline (152.992 us; speedup 1.0000x reference)
//
#include <hip/hip_runtime.h>
#include <hip/hip_bf16.h>

#define B_   2
#define S_   2048
#define H_   1024
#define NH_  16
#define HD_  64
#define MTOT 4096
#define KD   1024

typedef __attribute__((ext_vector_type(4)))  float    f32x4;
typedef __attribute__((ext_vector_type(16))) float    f32x16;
typedef __attribute__((ext_vector_type(8)))  short    bf16x8;
typedef __attribute__((ext_vector_type(2)))  unsigned u32x2;
typedef __attribute__((ext_vector_type(4)))  unsigned u32x4;

// f32 -> bf16 RNE (exact bit-math; BW-bound converters)
__device__ inline short f2bf(float x) {
    union { float f; unsigned u; } v; v.f = x;
    unsigned r = v.u + 0x7fffu + ((v.u >> 16) & 1u);
    return (short)(r >> 16);
}
__device__ inline unsigned pk2(float lo, float hi) {
    return (unsigned)(unsigned short)f2bf(lo) | ((unsigned)(unsigned short)f2bf(hi) << 16);
}
// HW pack: 2 f32 -> u32 of 2 bf16 (compute-bound loops)
__device__ inline unsigned cvtpk(float lo, float hi) {
    unsigned r;
    asm("v_cvt_pk_bf16_f32 %0, %1, %2" : "=v"(r) : "v"(lo), "v"(hi));
    return r;
}
__device__ inline float max3f(float a, float b, float c) {
    float r;
    asm("v_max3_f32 %0, %1, %2, %3" : "=v"(r) : "v"(a), "v"(b), "v"(c));
    return r;
}
// async global->LDS, 16B/lane; LDS dest wave-uniform base + lane*16
__device__ inline void gload16(const void* g, void* l) {
    __builtin_amdgcn_global_load_lds(
        (const __attribute__((address_space(1))) unsigned*)g,
        (__attribute__((address_space(3))) unsigned*)l, 16, 0, 0);
}

// ---------------------------------------------------------------------------
__global__ __launch_bounds__(256) void cvt_x(const float* __restrict__ x,
                                             unsigned* __restrict__ xb) {
    const size_t i = ((size_t)blockIdx.x * 256 + threadIdx.x) * 8;
    const f32x4 a = *(const f32x4*)(x + i);
    const f32x4 b = *(const f32x4*)(x + i + 4);
    u32x4 p;
    p[0] = pk2(a[0], a[1]); p[1] = pk2(a[2], a[3]);
    p[2] = pk2(b[0], b[1]); p[3] = pk2(b[2], b[3]);
    *(u32x4*)(xb + i / 2) = p;
}

__global__ __launch_bounds__(256) void wcvt(const float* __restrict__ W0,
                                            const float* __restrict__ W1,
                                            const float* __restrict__ W2,
                                            const float* __restrict__ W3,
                                            unsigned* __restrict__ wb) {
    const float* W = (blockIdx.y == 0) ? W0 : (blockIdx.y == 1) ? W1
                   : (blockIdx.y == 2) ? W2 : W3;
    const size_t i = ((size_t)blockIdx.x * 256 + threadIdx.x) * 8;
    const f32x4 a = *(const f32x4*)(W + i);
    const f32x4 b = *(const f32x4*)(W + i + 4);
    u32x4 p;
    p[0] = pk2(a[0], a[1]); p[1] = pk2(a[2], a[3]);
    p[2] = pk2(b[0], b[1]); p[3] = pk2(b[2], b[3]);
    *(u32x4*)(wb + (size_t)blockIdx.y * (H_ * KD / 2) + i / 2) = p;
}

// ---------------------------------------------------------------------------
// GEMM  C[m][n] = sum_k A[m][k] * W[n][k],  A and W both bf16 (m97 structure).
// ---------------------------------------------------------------------------
template <int MODE>
__global__ __launch_bounds__(256) void gemm_m97(const short* __restrict__ A,
                                                const short* __restrict__ Wb,
                                                short* __restrict__ outb,
                                                float* __restrict__ outf) {
    __shared__ short Sm[128 * 128];
    short* As = Sm;
    short* Bs = Sm + 8192;

    const int tid = threadIdx.x, wave = tid >> 6, lane = tid & 63;
    const int wm = (wave >> 1) * 64, wn = (wave & 1) * 64;
    const int m0 = blockIdx.x * 128;

    int n0, widx;
    if constexpr (MODE == 0) {
        widx = blockIdx.y >> 3;
        n0 = (blockIdx.y & 7) * 128;
    } else {
        widx = 0;
        n0 = blockIdx.y * 128;
    }
    const short* W = Wb + (size_t)widx * H_ * KD;

    f32x4 acc[4][4] = {};

    for (int k0 = 0; k0 < KD; k0 += 64) {
#pragma unroll
        for (int c = 0; c < 4; ++c) {
            const int lin = wave * 4096 + c * 1024 + lane * 16;
            const int row = lin >> 7;
            const int col = (lin & 127) ^ ((row & 7) << 4);
            gload16(A + (size_t)(m0 + row) * KD + k0 + (col >> 1),
                    (char*)As + wave * 4096 + c * 1024);
            gload16(W + (size_t)(n0 + row) * KD + k0 + (col >> 1),
                    (char*)Bs + wave * 4096 + c * 1024);
        }
        __syncthreads();

#pragma unroll
        for (int ks = 0; ks < 2; ++ks) {
            bf16x8 af[4], bf[4];
#pragma unroll
            for (int i = 0; i < 4; ++i) {
                const int row = wm + i * 16 + (lane & 15);
                af[i] = *(const bf16x8*)((char*)As + row * 128 +
                        ((ks * 64 + (lane >> 4) * 16) ^ ((row & 7) << 4)));
            }
#pragma unroll
            for (int j = 0; j < 4; ++j) {
                const int row = wn + j * 16 + (lane & 15);
                bf[j] = *(const bf16x8*)((char*)Bs + row * 128 +
                        ((ks * 64 + (lane >> 4) * 16) ^ ((row & 7) << 4)));
            }
#pragma unroll
            for (int i = 0; i < 4; ++i)
#pragma unroll
                for (int j = 0; j < 4; ++j)
                    acc[i][j] = __builtin_amdgcn_mfma_f32_16x16x32_bf16(af[i], bf[j], acc[i][j], 0, 0, 0);
        }
        __syncthreads();
    }

    if constexpr (MODE == 0) {
#pragma unroll
        for (int i = 0; i < 4; ++i)
#pragma unroll
            for (int j = 0; j < 4; ++j)
#pragma unroll
                for (int r = 0; r < 4; ++r) {
                    const int mi = wm + i * 16 + (lane >> 4) * 4 + r;
                    const int ni = wn + j * 16 + (lane & 15);
                    const int byt = (mi * 256 + ni * 2) ^ ((mi & 7) << 4);
                    *(short*)((char*)Sm + byt) = f2bf(acc[i][j][r]);
                }
        __syncthreads();
        const int row = tid >> 1, half = tid & 1;
        const int m = m0 + row, bb = m >> 11, s = m & 2047;
        const int hh = (n0 >> 6) + half;
        short* dst = outb + (size_t)widx * MTOT * H_ +
                     (((size_t)(bb * NH_ + hh)) * S_ + s) * HD_;
#pragma unroll
        for (int k = 0; k < 8; ++k) {
            const int byt = (row * 256 + half * 128 + k * 16) ^ ((row & 7) << 4);
            *(bf16x8*)(dst + k * 8) = *(const bf16x8*)((char*)Sm + byt);
        }
    } else {
#pragma unroll
        for (int i = 0; i < 4; ++i)
#pragma unroll
            for (int j = 0; j < 4; ++j)
#pragma unroll
                for (int r = 0; r < 4; ++r) {
                    const int m = m0 + wm + i * 16 + (lane >> 4) * 4 + r;
                    const int n = n0 + wn + j * 16 + (lane & 15);
                    outf[(size_t)m * H_ + n] = acc[i][j][r];
                }
    }
}

// ---------------------------------------------------------------------------
// Flash attention, causal, swapped-operand 32x32 MFMA, in-block KV-split.
// grid = 512 (pair-remapped), 512 threads = 8 waves.
// wave -> (qg = wave&3: q rows qg*32..+31, half = wave>>2: kv range half).
// half 0: kv tiles 0..qt ; half 1: kv tiles qt+1..2qt+1.  Uniform qt+1 iters.
// Partial (m,l,O^T) merged through LDS at the end.
// ---------------------------------------------------------------------------
__global__ __launch_bounds__(512, 4) void flash3(const short* __restrict__ Qb,
                                                 const short* __restrict__ Kb,
                                                 const short* __restrict__ Vb,
                                                 short* __restrict__ Ob) {
    const int bx = blockIdx.x;
    const int hi = bx >> 8, u = bx & 255;
    const int h = u >> 4, tq = u & 15;
    const int qt = hi ? (15 - tq) : tq;
    const int b  = hi;

    const int tid = threadIdx.x, wave = tid >> 6, lane = tid & 63;
    const int qg = wave & 3, half = wave >> 2;
    const int th = tid & 255;                 // thread index within half
    const int q0 = qt * 128;
    const int qw0 = q0 + qg * 32;
    const size_t hoff = ((size_t)(b * NH_ + h)) * S_ * HD_;
    const short* Q = Qb + hoff;
    const short* K = Kb + hoff;
    const short* V = Vb + hoff;

    __shared__ short Ks[2][2][4096];   // [half][buf][key][d], XOR-swizzled
    __shared__ short Vt[2][2][4096];   // [half][buf][d][key], XOR-swizzled

    const int ql = lane & 31;
    const int hh = lane >> 5;

    bf16x8 qf[4];
#pragma unroll
    for (int ds = 0; ds < 4; ++ds)
        qf[ds] = *(const bf16x8*)(Q + (size_t)(qw0 + ql) * HD_ + ds * 16 + hh * 8);

    f32x16 ot[2] = {};
    float mrun = -1e30f, lrun = 0.f;
    const float c2 = 0.18033688011112042f;   // 0.125 * log2(e)

    const int kk = (th & 31) * 2, d0v = (th >> 5) * 8;
    bf16x8 vr0, vr1;
    auto stageK = [&](int kt, int buf) {
#pragma unroll
        for (int c = 0; c < 2; ++c) {
            const int lin = qg * 2048 + c * 1024 + lane * 16;
            const int row = lin >> 7;
            const int col = (lin & 127) ^ ((row & 7) << 4);
            gload16(K + (size_t)(kt * 64 + row) * HD_ + (col >> 1),
                    (char*)Ks[half][buf] + qg * 2048 + c * 1024);
        }
    };
    auto loadV = [&](int kt) {
        vr0 = *(const bf16x8*)(V + (size_t)(kt * 64 + kk) * HD_ + d0v);
        vr1 = *(const bf16x8*)(V + (size_t)(kt * 64 + kk + 1) * HD_ + d0v);
    };
    auto writeV = [&](int buf) {
#pragma unroll
        for (int i = 0; i < 8; ++i) {
            const int d = d0v + i;
            const int byt = d * 128 + kk * 2;
            *(unsigned*)((char*)Vt[half][buf] + (byt ^ ((d & 7) << 4))) =
                (unsigned)(unsigned short)vr0[i] | ((unsigned)(unsigned short)vr1[i] << 16);
        }
    };

    const int niter = qt + 1;
    const int ktbase = half ? (qt + 1) : 0;

    stageK(ktbase, 0);
    loadV(ktbase);
    writeV(0);
    __syncthreads();

    int cur = 0;
    for (int it = 0; it < niter; ++it) {
        const int kt = ktbase + it;
        const bool pre = (it + 1 < niter);
        if (pre) { stageK(kt + 1, cur ^ 1); loadV(kt + 1); }

        if (kt * 64 <= qw0 + 31) {
            const bool need_mask = (kt * 64 + 63) > qw0;

            f32x16 st[2] = {};
            __builtin_amdgcn_s_setprio(1);
#pragma unroll
            for (int t = 0; t < 2; ++t)
#pragma unroll
                for (int ds = 0; ds < 4; ++ds) {
                    const int row = t * 32 + ql;
                    const bf16x8 kf = *(const bf16x8*)((char*)Ks[half][cur] + row * 128 +
                            ((ds * 32 + hh * 16) ^ ((row & 7) << 4)));
                    st[t] = __builtin_amdgcn_mfma_f32_32x32x16_bf16(kf, qf[ds], st[t], 0, 0, 0);
                }
            __builtin_amdgcn_s_setprio(0);

            float sraw[32];
#pragma unroll
            for (int t = 0; t < 2; ++t)
#pragma unroll
                for (int r = 0; r < 16; ++r) {
                    float v = st[t][r];
                    if (need_mask) {
                        const int key = kt * 64 + t * 32 + (r & 3) + 8 * (r >> 2) + 4 * hh;
                        if (key > qw0 + ql) v = -1e30f;
                    }
                    sraw[t * 16 + r] = v;
                }

            float ma = fmaxf(sraw[0], sraw[1]);
            float mb = fmaxf(sraw[2], sraw[3]);
#pragma unroll
            for (int i = 4; i < 32; i += 4) {
                ma = max3f(ma, sraw[i],     sraw[i + 1]);
                mb = max3f(mb, sraw[i + 2], sraw[i + 3]);
            }
            const float pmax = fmaxf(fmaxf(ma, mb), __shfl_xor(fmaxf(ma, mb), 32, 64));

            if (!__all((pmax - mrun) <= 44.36f)) {
                const float mnew = fmaxf(mrun, pmax);
                const float corr = exp2f((mrun - mnew) * c2);
                mrun = mnew;
                lrun *= corr;
#pragma unroll
                for (int dt = 0; dt < 2; ++dt)
#pragma unroll
                    for (int r = 0; r < 16; ++r) ot[dt][r] *= corr;
            }
            const float mc = mrun * c2;

            float p[32];
#pragma unroll
            for (int i = 0; i < 32; ++i) p[i] = exp2f(fmaf(sraw[i], c2, -mc));
            float ts[16];
#pragma unroll
            for (int i = 0; i < 16; ++i) ts[i] = p[i] + p[i + 16];
#pragma unroll
            for (int stp = 8; stp >= 1; stp >>= 1)
#pragma unroll
                for (int i = 0; i < 8; ++i)
                    if (i < stp) ts[i] += ts[i + stp];
            lrun += ts[0] + __shfl_xor(ts[0], 32, 64);

#pragma unroll
            for (int ks = 0; ks < 4; ++ks) {
                const int t = ks >> 1, rb = (ks & 1) * 8;
                const unsigned a0 = cvtpk(p[t * 16 + rb + 0], p[t * 16 + rb + 1]);
                const unsigned a1 = cvtpk(p[t * 16 + rb + 2], p[t * 16 + rb + 3]);
                const unsigned a2 = cvtpk(p[t * 16 + rb + 4], p[t * 16 + rb + 5]);
                const unsigned a3 = cvtpk(p[t * 16 + rb + 6], p[t * 16 + rb + 7]);
                const unsigned s0 = __shfl_xor(a0, 32, 64);
                const unsigned s1 = __shfl_xor(a1, 32, 64);
                const unsigned s2 = __shfl_xor(a2, 32, 64);
                const unsigned s3 = __shfl_xor(a3, 32, 64);
                u32x4 pw;
                pw[0] = hh ? s2 : a0;
                pw[1] = hh ? s3 : a1;
                pw[2] = hh ? a2 : s0;
                pw[3] = hh ? a3 : s1;
                const bf16x8 pf = __builtin_bit_cast(bf16x8, pw);
                __builtin_amdgcn_s_setprio(1);
#pragma unroll
                for (int dt = 0; dt < 2; ++dt) {
                    const int row = dt * 32 + ql;
                    const bf16x8 vf = *(const bf16x8*)((char*)Vt[half][cur] + row * 128 +
                            ((ks * 32 + hh * 16) ^ ((row & 7) << 4)));
                    ot[dt] = __builtin_amdgcn_mfma_f32_32x32x16_bf16(vf, pf, ot[dt], 0, 0, 0);
                }
                __builtin_amdgcn_s_setprio(0);
            }
        }

        if (pre) writeV(cur ^ 1);
        __syncthreads();
        cur ^= 1;
    }

    // ---- merge the two kv-halves (overlay LDS), then epilogue ----
    float* Osh = (float*)Ks;              // 4 groups x 64 lanes x 32 f32 = 32 KB
    float* Msh = (float*)Vt;              // 4 groups x 64 lanes x {m,l}
    const int swz = (lane & 7) << 2;      // float-unit XOR swizzle (16B granules)

    if (half == 1) {
        float* dst = Osh + ((size_t)qg * 64 + lane) * 32;
#pragma unroll
        for (int dt = 0; dt < 2; ++dt)
#pragma unroll
            for (int g4 = 0; g4 < 4; ++g4) {
                f32x4 t;
                t[0] = ot[dt][g4 * 4 + 0]; t[1] = ot[dt][g4 * 4 + 1];
                t[2] = ot[dt][g4 * 4 + 2]; t[3] = ot[dt][g4 * 4 + 3];
                *(f32x4*)(dst + ((dt * 16 + g4 * 4) ^ swz)) = t;
            }
        Msh[(qg * 64 + lane) * 2 + 0] = mrun;
        Msh[(qg * 64 + lane) * 2 + 1] = lrun;
    }
    __syncthreads();

    if (half == 0) {
        const float* src = Osh + ((size_t)qg * 64 + lane) * 32;
        const float mB = Msh[(qg * 64 + lane) * 2 + 0];
        const float lB = Msh[(qg * 64 + lane) * 2 + 1];
        const float m  = fmaxf(mrun, mB);
        const float al = exp2f((mrun - m) * c2);
        const float be = exp2f((mB   - m) * c2);
        const float inv = 1.f / (al * lrun + be * lB);
        const float ai = al * inv, bi = be * inv;

        short* orow = Ob + ((size_t)(b * S_) + q0 + qg * 32 + ql) * H_ + h * HD_;
#pragma unroll
        for (int dt = 0; dt < 2; ++dt)
#pragma unroll
            for (int g4 = 0; g4 < 4; ++g4) {
                const f32x4 ob = *(const f32x4*)(src + ((dt * 16 + g4 * 4) ^ swz));
                const int dbase = dt * 32 + 8 * g4 + 4 * hh;
                u32x2 w;
                w[0] = cvtpk(ot[dt][g4 * 4 + 0] * ai + ob[0] * bi,
                             ot[dt][g4 * 4 + 1] * ai + ob[1] * bi);
                w[1] = cvtpk(ot[dt][g4 * 4 + 2] * ai + ob[2] * bi,
                             ot[dt][g4 * 4 + 3] * ai + ob[3] * bi);
                *(u32x2*)(orow + dbase) = w;
            }
    }
}

// ---------------------------------------------------------------------------
extern "C" void kernel_launch(void* const* d_in, const int* in_sizes, int n_in,
                              void* d_out, int out_size, void* d_ws, size_t ws_size,
                              hipStream_t stream) {
    const float* x  = (const float*)d_in[0];
    const float* Wq = (const float*)d_in[2];
    const float* Wk = (const float*)d_in[3];
    const float* Wv = (const float*)d_in[4];
    const float* Wo = (const float*)d_in[5];
    float* out = (float*)d_out;

    short* qkv = (short*)d_ws;
    short* xb  = qkv + (size_t)3 * MTOT * H_;
    short* wb  = xb + (size_t)MTOT * H_;

    cvt_x<<<2048, 256, 0, stream>>>(x, (unsigned*)xb);
    wcvt<<<dim3(512, 4), 256, 0, stream>>>(Wq, Wk, Wv, Wo, (unsigned*)wb);

    gemm_m97<0><<<dim3(32, 24), 256, 0, stream>>>(xb, wb, qkv, nullptr);

    flash3<<<dim3(512), 512, 0, stream>>>(
        qkv, qkv + (size_t)MTOT * H_, qkv + (size_t)2 * MTOT * H_, xb);

    gemm_m97<1><<<dim3(32, 8), 256, 0, stream>>>(
        xb, wb + (size_t)3 * H_ * KD, nullptr, out);
}

// Round 7
// 147.751 us; speedup vs baseline: 1.0355x; 1.0355x over previous
//
#include <hip/hip_runtime.h>
#include <hip/hip_bf16.h>

#define B_   2
#define S_   2048
#define H_   1024
#define NH_  16
#define HD_  64
#define MTOT 4096
#define KD   1024

typedef __attribute__((ext_vector_type(4)))  float    f32x4;
typedef __attribute__((ext_vector_type(16))) float    f32x16;
typedef __attribute__((ext_vector_type(8)))  short    bf16x8;
typedef __attribute__((ext_vector_type(2)))  unsigned u32x2;
typedef __attribute__((ext_vector_type(4)))  unsigned u32x4;

// f32 -> bf16 RNE (exact bit-math; BW-bound converters)
__device__ inline short f2bf(float x) {
    union { float f; unsigned u; } v; v.f = x;
    unsigned r = v.u + 0x7fffu + ((v.u >> 16) & 1u);
    return (short)(r >> 16);
}
__device__ inline unsigned pk2(float lo, float hi) {
    return (unsigned)(unsigned short)f2bf(lo) | ((unsigned)(unsigned short)f2bf(hi) << 16);
}
// HW pack: 2 f32 -> u32 of 2 bf16 (compute-bound loops)
__device__ inline unsigned cvtpk(float lo, float hi) {
    unsigned r;
    asm("v_cvt_pk_bf16_f32 %0, %1, %2" : "=v"(r) : "v"(lo), "v"(hi));
    return r;
}
__device__ inline float max3f(float a, float b, float c) {
    float r;
    asm("v_max3_f32 %0, %1, %2, %3" : "=v"(r) : "v"(a), "v"(b), "v"(c));
    return r;
}
// async global->LDS, 16B/lane; LDS dest wave-uniform base + lane*16
__device__ inline void gload16(const void* g, void* l) {
    __builtin_amdgcn_global_load_lds(
        (const __attribute__((address_space(1))) unsigned*)g,
        (__attribute__((address_space(3))) unsigned*)l, 16, 0, 0);
}

// ---------------------------------------------------------------------------
__global__ __launch_bounds__(256) void cvt_x(const float* __restrict__ x,
                                             unsigned* __restrict__ xb) {
    const size_t i = ((size_t)blockIdx.x * 256 + threadIdx.x) * 8;
    const f32x4 a = *(const f32x4*)(x + i);
    const f32x4 b = *(const f32x4*)(x + i + 4);
    u32x4 p;
    p[0] = pk2(a[0], a[1]); p[1] = pk2(a[2], a[3]);
    p[2] = pk2(b[0], b[1]); p[3] = pk2(b[2], b[3]);
    *(u32x4*)(xb + i / 2) = p;
}

__global__ __launch_bounds__(256) void wcvt(const float* __restrict__ W0,
                                            const float* __restrict__ W1,
                                            const float* __restrict__ W2,
                                            const float* __restrict__ W3,
                                            unsigned* __restrict__ wb) {
    const float* W = (blockIdx.y == 0) ? W0 : (blockIdx.y == 1) ? W1
                   : (blockIdx.y == 2) ? W2 : W3;
    const size_t i = ((size_t)blockIdx.x * 256 + threadIdx.x) * 8;
    const f32x4 a = *(const f32x4*)(W + i);
    const f32x4 b = *(const f32x4*)(W + i + 4);
    u32x4 p;
    p[0] = pk2(a[0], a[1]); p[1] = pk2(a[2], a[3]);
    p[2] = pk2(b[0], b[1]); p[3] = pk2(b[2], b[3]);
    *(u32x4*)(wb + (size_t)blockIdx.y * (H_ * KD / 2) + i / 2) = p;
}

// ---------------------------------------------------------------------------
// GEMM  C[m][n] = sum_k A[m][k] * W[n][k],  A and W both bf16 (m97 structure).
// ---------------------------------------------------------------------------
template <int MODE>
__global__ __launch_bounds__(256) void gemm_m97(const short* __restrict__ A,
                                                const short* __restrict__ Wb,
                                                short* __restrict__ outb,
                                                float* __restrict__ outf) {
    __shared__ short Sm[128 * 128];
    short* As = Sm;
    short* Bs = Sm + 8192;

    const int tid = threadIdx.x, wave = tid >> 6, lane = tid & 63;
    const int wm = (wave >> 1) * 64, wn = (wave & 1) * 64;
    const int m0 = blockIdx.x * 128;

    int n0, widx;
    if constexpr (MODE == 0) {
        widx = blockIdx.y >> 3;
        n0 = (blockIdx.y & 7) * 128;
    } else {
        widx = 0;
        n0 = blockIdx.y * 128;
    }
    const short* W = Wb + (size_t)widx * H_ * KD;

    f32x4 acc[4][4] = {};

    for (int k0 = 0; k0 < KD; k0 += 64) {
#pragma unroll
        for (int c = 0; c < 4; ++c) {
            const int lin = wave * 4096 + c * 1024 + lane * 16;
            const int row = lin >> 7;
            const int col = (lin & 127) ^ ((row & 7) << 4);
            gload16(A + (size_t)(m0 + row) * KD + k0 + (col >> 1),
                    (char*)As + wave * 4096 + c * 1024);
            gload16(W + (size_t)(n0 + row) * KD + k0 + (col >> 1),
                    (char*)Bs + wave * 4096 + c * 1024);
        }
        __syncthreads();

#pragma unroll
        for (int ks = 0; ks < 2; ++ks) {
            bf16x8 af[4], bf[4];
#pragma unroll
            for (int i = 0; i < 4; ++i) {
                const int row = wm + i * 16 + (lane & 15);
                af[i] = *(const bf16x8*)((char*)As + row * 128 +
                        ((ks * 64 + (lane >> 4) * 16) ^ ((row & 7) << 4)));
            }
#pragma unroll
            for (int j = 0; j < 4; ++j) {
                const int row = wn + j * 16 + (lane & 15);
                bf[j] = *(const bf16x8*)((char*)Bs + row * 128 +
                        ((ks * 64 + (lane >> 4) * 16) ^ ((row & 7) << 4)));
            }
#pragma unroll
            for (int i = 0; i < 4; ++i)
#pragma unroll
                for (int j = 0; j < 4; ++j)
                    acc[i][j] = __builtin_amdgcn_mfma_f32_16x16x32_bf16(af[i], bf[j], acc[i][j], 0, 0, 0);
        }
        __syncthreads();
    }

    if constexpr (MODE == 0) {
#pragma unroll
        for (int i = 0; i < 4; ++i)
#pragma unroll
            for (int j = 0; j < 4; ++j)
#pragma unroll
                for (int r = 0; r < 4; ++r) {
                    const int mi = wm + i * 16 + (lane >> 4) * 4 + r;
                    const int ni = wn + j * 16 + (lane & 15);
                    const int byt = (mi * 256 + ni * 2) ^ ((mi & 7) << 4);
                    *(short*)((char*)Sm + byt) = f2bf(acc[i][j][r]);
                }
        __syncthreads();
        const int row = tid >> 1, half = tid & 1;
        const int m = m0 + row, bb = m >> 11, s = m & 2047;
        const int hh = (n0 >> 6) + half;
        short* dst = outb + (size_t)widx * MTOT * H_ +
                     (((size_t)(bb * NH_ + hh)) * S_ + s) * HD_;
#pragma unroll
        for (int k = 0; k < 8; ++k) {
            const int byt = (row * 256 + half * 128 + k * 16) ^ ((row & 7) << 4);
            *(bf16x8*)(dst + k * 8) = *(const bf16x8*)((char*)Sm + byt);
        }
    } else {
#pragma unroll
        for (int i = 0; i < 4; ++i)
#pragma unroll
            for (int j = 0; j < 4; ++j)
#pragma unroll
                for (int r = 0; r < 4; ++r) {
                    const int m = m0 + wm + i * 16 + (lane >> 4) * 4 + r;
                    const int n = n0 + wn + j * 16 + (lane & 15);
                    outf[(size_t)m * H_ + n] = acc[i][j][r];
                }
    }
}

// ---------------------------------------------------------------------------
// Flash attention, causal, swapped-operand 32x32 MFMA, PARITY-interleaved
// in-block KV-split: wave (qg = w&3, par = w>>2) computes tiles kt = 2*it+par
// of qg's causal range. Block stages a tile-PAIR per iteration; all 8 waves
// active. Partials merged through LDS. grid=512 (pair-remapped), 512 thr.
// ---------------------------------------------------------------------------
__global__ __launch_bounds__(512, 4) void flash4(const short* __restrict__ Qb,
                                                 const short* __restrict__ Kb,
                                                 const short* __restrict__ Vb,
                                                 short* __restrict__ Ob) {
    const int bx = blockIdx.x;
    const int hi = bx >> 8, u = bx & 255;
    const int h = u >> 4, tq = u & 15;
    const int qt = hi ? (15 - tq) : tq;
    const int b  = hi;

    const int tid = threadIdx.x, wave = tid >> 6, lane = tid & 63;
    const int qg = wave & 3, par = wave >> 2;
    const int q0 = qt * 128;
    const int qw0 = q0 + qg * 32;
    const size_t hoff = ((size_t)(b * NH_ + h)) * S_ * HD_;
    const short* Q = Qb + hoff;
    const short* K = Kb + hoff;
    const short* V = Vb + hoff;

    __shared__ short Ks[2][2][4096];   // [par][buf][key][d], XOR-swizzled
    __shared__ short Vt[2][2][4096];   // [par][buf][d][key], XOR-swizzled

    const int ql = lane & 31;
    const int hh = lane >> 5;

    bf16x8 qf[4];
#pragma unroll
    for (int ds = 0; ds < 4; ++ds)
        qf[ds] = *(const bf16x8*)(Q + (size_t)(qw0 + ql) * HD_ + ds * 16 + hh * 8);

    f32x16 ot[2] = {};
    float mrun = -1e30f, lrun = 0.f;
    const float c2 = 0.18033688011112042f;   // 0.125 * log2(e)

    // ---- staging: tile-pair (2j, 2j+1) -> buf j&1 ----
    auto stagePair = [&](int j) {             // K via gload_lds, 2 chunks/wave
        const int buf = j & 1;
#pragma unroll
        for (int c = 0; c < 2; ++c) {
            const int chunk = wave * 2 + c;   // 0..15
            const int pt  = chunk >> 3;       // which parity tile
            const int sub = chunk & 7;        // 1KB sub-chunk
            const int lin = sub * 1024 + lane * 16;
            const int row = lin >> 7;
            const int col = (lin & 127) ^ ((row & 7) << 4);
            gload16(K + (size_t)((2 * j + pt) * 64 + row) * HD_ + (col >> 1),
                    (char*)Ks[pt][buf] + sub * 1024);
        }
    };
    const int vpar = tid >> 8;                // V tile this thread stages
    const int kk = (tid & 31) * 2, d0v = ((tid >> 5) & 7) * 8;
    bf16x8 vr0, vr1;
    auto loadV = [&](int j) {
        const int kt = 2 * j + vpar;
        vr0 = *(const bf16x8*)(V + (size_t)(kt * 64 + kk) * HD_ + d0v);
        vr1 = *(const bf16x8*)(V + (size_t)(kt * 64 + kk + 1) * HD_ + d0v);
    };
    auto writeV = [&](int j) {
        const int buf = j & 1;
#pragma unroll
        for (int i = 0; i < 8; ++i) {
            const int d = d0v + i;
            const int byt = d * 128 + kk * 2;
            *(unsigned*)((char*)Vt[vpar][buf] + (byt ^ ((d & 7) << 4))) =
                (unsigned)(unsigned short)vr0[i] | ((unsigned)(unsigned short)vr1[i] << 16);
        }
    };

    const int niter = qt + 1;                 // uniform across waves

    stagePair(0);
    loadV(0);
    writeV(0);
    __syncthreads();

    for (int it = 0; it < niter; ++it) {
        const bool pre = (it + 1 < niter);
        if (pre) { stagePair(it + 1); loadV(it + 1); }

        const int kt = 2 * it + par;
        const int buf = it & 1;
        if (kt * 64 <= qw0 + 31) {
            const bool need_mask = (kt * 64 + 63) > qw0;

            f32x16 st[2] = {};
            __builtin_amdgcn_s_setprio(1);
#pragma unroll
            for (int t = 0; t < 2; ++t)
#pragma unroll
                for (int ds = 0; ds < 4; ++ds) {
                    const int row = t * 32 + ql;
                    const bf16x8 kf = *(const bf16x8*)((char*)Ks[par][buf] + row * 128 +
                            ((ds * 32 + hh * 16) ^ ((row & 7) << 4)));
                    st[t] = __builtin_amdgcn_mfma_f32_32x32x16_bf16(kf, qf[ds], st[t], 0, 0, 0);
                }
            __builtin_amdgcn_s_setprio(0);

            float sraw[32];
#pragma unroll
            for (int t = 0; t < 2; ++t)
#pragma unroll
                for (int r = 0; r < 16; ++r) {
                    float v = st[t][r];
                    if (need_mask) {
                        const int key = kt * 64 + t * 32 + (r & 3) + 8 * (r >> 2) + 4 * hh;
                        if (key > qw0 + ql) v = -1e30f;
                    }
                    sraw[t * 16 + r] = v;
                }

            float ma = fmaxf(sraw[0], sraw[1]);
            float mb = fmaxf(sraw[2], sraw[3]);
#pragma unroll
            for (int i = 4; i < 32; i += 4) {
                ma = max3f(ma, sraw[i],     sraw[i + 1]);
                mb = max3f(mb, sraw[i + 2], sraw[i + 3]);
            }
            const float pmax = fmaxf(fmaxf(ma, mb), __shfl_xor(fmaxf(ma, mb), 32, 64));

            if (!__all((pmax - mrun) <= 44.36f)) {
                const float mnew = fmaxf(mrun, pmax);
                const float corr = exp2f((mrun - mnew) * c2);
                mrun = mnew;
                lrun *= corr;
#pragma unroll
                for (int dt = 0; dt < 2; ++dt)
#pragma unroll
                    for (int r = 0; r < 16; ++r) ot[dt][r] *= corr;
            }
            const float mc = mrun * c2;

            float p[32];
#pragma unroll
            for (int i = 0; i < 32; ++i) p[i] = exp2f(fmaf(sraw[i], c2, -mc));
            float ts[16];
#pragma unroll
            for (int i = 0; i < 16; ++i) ts[i] = p[i] + p[i + 16];
#pragma unroll
            for (int stp = 8; stp >= 1; stp >>= 1)
#pragma unroll
                for (int i = 0; i < 8; ++i)
                    if (i < stp) ts[i] += ts[i + stp];
            lrun += ts[0] + __shfl_xor(ts[0], 32, 64);

#pragma unroll
            for (int ks = 0; ks < 4; ++ks) {
                const int t = ks >> 1, rb = (ks & 1) * 8;
                const unsigned a0 = cvtpk(p[t * 16 + rb + 0], p[t * 16 + rb + 1]);
                const unsigned a1 = cvtpk(p[t * 16 + rb + 2], p[t * 16 + rb + 3]);
                const unsigned a2 = cvtpk(p[t * 16 + rb + 4], p[t * 16 + rb + 5]);
                const unsigned a3 = cvtpk(p[t * 16 + rb + 6], p[t * 16 + rb + 7]);
                const unsigned s0 = __shfl_xor(a0, 32, 64);
                const unsigned s1 = __shfl_xor(a1, 32, 64);
                const unsigned s2 = __shfl_xor(a2, 32, 64);
                const unsigned s3 = __shfl_xor(a3, 32, 64);
                u32x4 pw;
                pw[0] = hh ? s2 : a0;
                pw[1] = hh ? s3 : a1;
                pw[2] = hh ? a2 : s0;
                pw[3] = hh ? a3 : s1;
                const bf16x8 pf = __builtin_bit_cast(bf16x8, pw);
                __builtin_amdgcn_s_setprio(1);
#pragma unroll
                for (int dt = 0; dt < 2; ++dt) {
                    const int row = dt * 32 + ql;
                    const bf16x8 vf = *(const bf16x8*)((char*)Vt[par][buf] + row * 128 +
                            ((ks * 32 + hh * 16) ^ ((row & 7) << 4)));
                    ot[dt] = __builtin_amdgcn_mfma_f32_32x32x16_bf16(vf, pf, ot[dt], 0, 0, 0);
                }
                __builtin_amdgcn_s_setprio(0);
            }
        }

        if (pre) writeV(it + 1);
        __syncthreads();
    }

    // ---- merge parity partials (overlay LDS), then epilogue ----
    float* Osh = (float*)Ks;              // 4 groups x 64 lanes x 32 f32 = 32 KB
    float* Msh = (float*)Vt;              // 4 groups x 64 lanes x {m,l}
    const int swz = (lane & 7) << 2;      // float-unit XOR swizzle

    if (par == 1) {
        float* dst = Osh + ((size_t)qg * 64 + lane) * 32;
#pragma unroll
        for (int dt = 0; dt < 2; ++dt)
#pragma unroll
            for (int g4 = 0; g4 < 4; ++g4) {
                f32x4 t;
                t[0] = ot[dt][g4 * 4 + 0]; t[1] = ot[dt][g4 * 4 + 1];
                t[2] = ot[dt][g4 * 4 + 2]; t[3] = ot[dt][g4 * 4 + 3];
                *(f32x4*)(dst + ((dt * 16 + g4 * 4) ^ swz)) = t;
            }
        Msh[(qg * 64 + lane) * 2 + 0] = mrun;
        Msh[(qg * 64 + lane) * 2 + 1] = lrun;
    }
    __syncthreads();

    if (par == 0) {
        const float* src = Osh + ((size_t)qg * 64 + lane) * 32;
        const float mB = Msh[(qg * 64 + lane) * 2 + 0];
        const float lB = Msh[(qg * 64 + lane) * 2 + 1];
        const float m  = fmaxf(mrun, mB);
        const float al = exp2f((mrun - m) * c2);
        const float be = exp2f((mB   - m) * c2);
        const float inv = 1.f / (al * lrun + be * lB);
        const float ai = al * inv, bi = be * inv;

        short* orow = Ob + ((size_t)(b * S_) + q0 + qg * 32 + ql) * H_ + h * HD_;
#pragma unroll
        for (int dt = 0; dt < 2; ++dt)
#pragma unroll
            for (int g4 = 0; g4 < 4; ++g4) {
                const f32x4 ob = *(const f32x4*)(src + ((dt * 16 + g4 * 4) ^ swz));
                const int dbase = dt * 32 + 8 * g4 + 4 * hh;
                u32x2 w;
                w[0] = cvtpk(ot[dt][g4 * 4 + 0] * ai + ob[0] * bi,
                             ot[dt][g4 * 4 + 1] * ai + ob[1] * bi);
                w[1] = cvtpk(ot[dt][g4 * 4 + 2] * ai + ob[2] * bi,
                             ot[dt][g4 * 4 + 3] * ai + ob[3] * bi);
                *(u32x2*)(orow + dbase) = w;
            }
    }
}

// ---------------------------------------------------------------------------
extern "C" void kernel_launch(void* const* d_in, const int* in_sizes, int n_in,
                              void* d_out, int out_size, void* d_ws, size_t ws_size,
                              hipStream_t stream) {
    const float* x  = (const float*)d_in[0];
    const float* Wq = (const float*)d_in[2];
    const float* Wk = (const float*)d_in[3];
    const float* Wv = (const float*)d_in[4];
    const float* Wo = (const float*)d_in[5];
    float* out = (float*)d_out;

    short* qkv = (short*)d_ws;
    short* xb  = qkv + (size_t)3 * MTOT * H_;
    short* wb  = xb + (size_t)MTOT * H_;

    cvt_x<<<2048, 256, 0, stream>>>(x, (unsigned*)xb);
    wcvt<<<dim3(512, 4), 256, 0, stream>>>(Wq, Wk, Wv, Wo, (unsigned*)wb);

    gemm_m97<0><<<dim3(32, 24), 256, 0, stream>>>(xb, wb, qkv, nullptr);

    flash4<<<dim3(512), 512, 0, stream>>>(
        qkv, qkv + (size_t)MTOT * H_, qkv + (size_t)2 * MTOT * H_, xb);

    gemm_m97<1><<<dim3(32, 8), 256, 0, stream>>>(
        xb, wb + (size_t)3 * H_ * KD, nullptr, out);
}